// Round 3
// baseline (305.714 us; speedup 1.0000x reference)
//
#include <hip/hip_runtime.h>
#include <math.h>

// infoFSM mask-scorer MLP — Round 5: R4 + fast-erf gelu in pass B + input
// kept in registers for the out-epilogue.
//
// R4 (253us main): MfmaUtil 30 (matches 26% MFMA floor model), VALUBusy 42.
// VALU audit says libm erff (~50-60 branchy ops) is ~half the VALU time.
// Pass-B gelu only affects the decision bit, which the band (1e-3) + exact
// fix pass protect; bf16 hi/lo storage error (~1e-5) already dominates. So:
//  - pass B uses A&S 7.1.26 erf (|err|<=1.5e-7, ~14 ops, v_rcp + v_exp).
//    Fix pass keeps libm erff (same numeric class as before).
//  - staging keeps the 8 input float4 in registers; epilogue reuses them
//    (drops the 134MB second input read; VGPR ~64->~100, cap 128 ok).

namespace {

constexpr int R_ROWS = 128 * 512;   // 65536
constexpr int D0 = 512, D1 = 512, D2 = 256, D3 = 128;
constexpr int TM = 32;              // rows per block (pass B)
constexpr int NT = 512;             // 8 waves

typedef __attribute__((ext_vector_type(8)))  short          vshort8;
typedef __attribute__((ext_vector_type(4)))  unsigned short vus4;
typedef __attribute__((ext_vector_type(8)))  unsigned short vus8;
typedef __attribute__((ext_vector_type(16))) float          vf16;
typedef __attribute__((ext_vector_type(4)))  float          vf4;

// ---------------- helpers ----------------
__device__ __forceinline__ unsigned short f32_to_bf16(float x) {
    unsigned int b = __float_as_uint(x);
    b += 0x7FFFu + ((b >> 16) & 1u);          // RNE (inputs finite)
    return (unsigned short)(b >> 16);
}
__device__ __forceinline__ float bf16_to_f32(unsigned short h) {
    return __uint_as_float(((unsigned int)h) << 16);
}
__device__ __forceinline__ float gelu_exact(float x) {
    return 0.5f * x * (1.0f + erff(x * 0.70710678118654752440f));
}
// A&S 7.1.26 erf: |abs err| <= 1.5e-7 (+~2e-7 from rcp/exp rounding).
// Activation error ~1e-6 << bf16 hi/lo storage error (~1e-5) << band (1e-3).
__device__ __forceinline__ float gelu_fast(float x) {
    const float s = fabsf(x) * 0.70710678118654752440f;
    const float t = __builtin_amdgcn_rcpf(fmaf(0.3275911f, s, 1.0f));
    float p = fmaf(1.061405429f, t, -1.453152027f);
    p = fmaf(p, t, 1.421413741f);
    p = fmaf(p, t, -0.284496736f);
    p = fmaf(p, t, 0.254829592f);
    p *= t;
    const float e = __builtin_amdgcn_exp2f(s * s * -1.44269504088896341f);
    float er = fmaf(-p, e, 1.0f);             // erf(|x|/sqrt2)
    er = copysignf(er, x);
    return 0.5f * x * (1.0f + er);
}
__device__ __forceinline__ vf16 vzero16() {
    vf16 v;
    #pragma unroll
    for (int i = 0; i < 16; ++i) v[i] = 0.0f;
    return v;
}
__device__ __forceinline__ vf4 vzero4() {
    vf4 v;
    #pragma unroll
    for (int i = 0; i < 4; ++i) v[i] = 0.0f;
    return v;
}

// LDS activation tiles: [row][k] bf16, XOR-swizzle bits 4..6.
__device__ __forceinline__ int swz_off(int row, int colElem, int pitchB) {
    return (row * pitchB + colElem * 2) ^ ((row & 7) << 4);
}
__device__ __forceinline__ vshort8 ld_act32(const char* base, int lane, int pitchB, int k0) {
    const int row = lane & 31;
    const int k = k0 + ((lane >> 5) << 3);
    return *(const vshort8*)(base + swz_off(row, k, pitchB));
}
__device__ __forceinline__ vshort8 ld_act16(const char* base, int lane, int pitchB, int row0, int k0) {
    const int row = row0 + (lane & 15);
    const int k = k0 + ((lane >> 4) << 3);
    return *(const vshort8*)(base + swz_off(row, k, pitchB));
}
// packed weight fragment: P + blk*2048B + part*1024B + lane*16B
__device__ __forceinline__ vshort8 ld_pack(const unsigned short* __restrict__ P,
                                           int blk, int part, int lane) {
    return *(const vshort8*)((const char*)P + (((size_t)blk) << 11) +
                             (part << 10) + (lane << 4));
}
__device__ __forceinline__ void st_act(char* hi, char* lo, int row, int col, int pitchB, float x) {
    const unsigned short h = f32_to_bf16(x);
    const unsigned short l = f32_to_bf16(x - bf16_to_f32(h));
    const int off = swz_off(row, col, pitchB);
    *(unsigned short*)(hi + off) = h;
    *(unsigned short*)(lo + off) = l;
}

#define MFMA32(a, b, c) __builtin_amdgcn_mfma_f32_32x32x16_bf16((a), (b), (c), 0, 0, 0)
#define MFMA16(a, b, c) __builtin_amdgcn_mfma_f32_16x16x32_bf16((a), (b), (c), 0, 0, 0)

constexpr float BAND = 1e-3f;   // on v = prob*prev_m; ~70x est. bf16x3+gelu err

// ---------------- pass A: split + pack weights into fragment order ----------
__global__ __launch_bounds__(256) void pack_weights(
    const float* __restrict__ W_L, const float* __restrict__ W_l1,
    const float* __restrict__ W_l2,
    unsigned short* __restrict__ P1, unsigned short* __restrict__ P2,
    unsigned short* __restrict__ P3)
{
    const int g = blockIdx.x * 256 + threadIdx.x;   // 53248 threads total
    const float* src;
    unsigned short* dst;
    int e, k, K, blk, lane;
    if (g < 32768) {
        lane = g & 63;
        const int ks = (g >> 6) & 31, nt = g >> 11;
        src = W_L; K = 512; dst = P1;
        e = nt * 32 + (lane & 31);
        k = ks * 16 + ((lane >> 5) << 3);
        blk = nt * 32 + ks;
    } else if (g < 49152) {
        const int h = g - 32768;
        lane = h & 63;
        const int ks = (h >> 6) & 31, nt = h >> 11;
        src = W_l1; K = 512; dst = P2;
        e = nt * 32 + (lane & 31);
        k = ks * 16 + ((lane >> 5) << 3);
        blk = nt * 32 + ks;
    } else {
        const int h = g - 49152;
        lane = h & 63;
        const int ks = (h >> 6) & 7, nt = h >> 9;
        src = W_l2; K = 256; dst = P3;
        e = nt * 16 + (lane & 15);
        k = ks * 32 + ((lane >> 4) << 3);
        blk = nt * 8 + ks;
    }
    const float4 v0 = *(const float4*)&src[(size_t)e * K + k];
    const float4 v1 = *(const float4*)&src[(size_t)e * K + k + 4];
    const float xs[8] = {v0.x, v0.y, v0.z, v0.w, v1.x, v1.y, v1.z, v1.w};
    vus8 hv, lv;
    #pragma unroll
    for (int j = 0; j < 8; ++j) {
        const unsigned short h = f32_to_bf16(xs[j]);
        hv[j] = h;
        lv[j] = f32_to_bf16(xs[j] - bf16_to_f32(h));
    }
    unsigned short* base = dst + ((size_t)blk << 10);   // 1024 shorts per blk
    *(vus8*)(base + lane * 8)       = hv;
    *(vus8*)(base + 512 + lane * 8) = lv;
}

// ---------------- pass B: fused MFMA MLP ----------------
// LDS overlay (bytes), one 64KB region:
//   stage A:  Ahi [0,32K)   Alo [32K,64K)        pitch 1024
//   GEMM1 ep: X1h [0,32K)   X1l [32K,64K)        pitch 1024  (A dead, barrier)
//   GEMM2 ep: X2h [0,16K)   X2l [16K,32K)        pitch 512   (X1 dead, barrier)
//   GEMM3 ep: X3  [32K, 32K+16896) f32 pitch 132 (disjoint from X2)
//   sM at [49664, 49792)
constexpr int SMEM_BYTES = 65536;

__global__ __launch_bounds__(NT, 4) void mlp_mfma(
    const float* __restrict__ input, const float* __restrict__ prev_m,
    const float* __restrict__ W_l3,
    const unsigned short* __restrict__ P1, const unsigned short* __restrict__ P2,
    const unsigned short* __restrict__ P3,
    float* __restrict__ out, float* __restrict__ mask_out, float* __restrict__ currm_out,
    unsigned int* __restrict__ ctr, int* __restrict__ list)
{
    __shared__ __attribute__((aligned(16))) char smem[SMEM_BYTES];
    char* Ahi = smem;
    char* Alo = smem + 32768;
    char* X1h = smem;
    char* X1l = smem + 32768;
    char* X2h = smem;
    char* X2l = smem + 16384;
    float* sX3 = (float*)(smem + 32768);      // [32][132] f32
    float* sM  = (float*)(smem + 49664);      // [32]

    const int tid  = threadIdx.x;
    const int lane = tid & 63;
    const int wid  = tid >> 6;
    const int row0 = blockIdx.x * TM;

    // ---- stage A: input rows -> bf16 hi/lo, swizzled; keep f32 in regs ----
    float4 fin[8];
    #pragma unroll
    for (int i = 0; i < 8; ++i) {
        const int c  = i * NT + tid;           // 0..4095 float4-chunks
        const int r  = c >> 7;
        const int kq = (c & 127) << 2;
        const float4 v = *(const float4*)&input[(size_t)(row0 + r) * D0 + kq];
        fin[i] = v;
        const unsigned short h0 = f32_to_bf16(v.x);
        const unsigned short h1 = f32_to_bf16(v.y);
        const unsigned short h2 = f32_to_bf16(v.z);
        const unsigned short h3 = f32_to_bf16(v.w);
        const unsigned short l0 = f32_to_bf16(v.x - bf16_to_f32(h0));
        const unsigned short l1 = f32_to_bf16(v.y - bf16_to_f32(h1));
        const unsigned short l2 = f32_to_bf16(v.z - bf16_to_f32(h2));
        const unsigned short l3 = f32_to_bf16(v.w - bf16_to_f32(h3));
        vus4 hv = {h0, h1, h2, h3};
        vus4 lv = {l0, l1, l2, l3};
        const int off = (r * 1024 + kq * 2) ^ ((r & 7) << 4);
        *(vus4*)(Ahi + off) = hv;
        *(vus4*)(Alo + off) = lv;
    }
    __syncthreads();   // B1: A staged

    // ---- GEMM1: X1 = gelu(A @ W_L^T), 32x512, K=512, 32x32x16 ----
    vf16 g1acc0, g1acc1;
    {
        const int nt0 = wid * 2;               // wave owns n-tiles nt0, nt0+1
        vf16 acc0 = vzero16(), acc1 = vzero16();
        #pragma unroll 4
        for (int ks = 0; ks < 32; ++ks) {
            const int k0 = ks * 16;
            vshort8 ah  = ld_act32(Ahi, lane, 1024, k0);
            vshort8 al  = ld_act32(Alo, lane, 1024, k0);
            vshort8 b0h = ld_pack(P1, nt0 * 32 + ks, 0, lane);
            vshort8 b0l = ld_pack(P1, nt0 * 32 + ks, 1, lane);
            vshort8 b1h = ld_pack(P1, (nt0 + 1) * 32 + ks, 0, lane);
            vshort8 b1l = ld_pack(P1, (nt0 + 1) * 32 + ks, 1, lane);
            acc0 = MFMA32(ah, b0h, acc0);
            acc1 = MFMA32(ah, b1h, acc1);
            acc0 = MFMA32(al, b0h, acc0);
            acc1 = MFMA32(al, b1h, acc1);
            acc0 = MFMA32(ah, b0l, acc0);
            acc1 = MFMA32(ah, b1l, acc1);
        }
        g1acc0 = acc0; g1acc1 = acc1;
    }
    __syncthreads();   // B2a: all waves done reading A
    {
        const int e0 = wid * 64;
        #pragma unroll
        for (int r = 0; r < 16; ++r) {
            const int row = (r & 3) + 8 * (r >> 2) + 4 * (lane >> 5);
            st_act(X1h, X1l, row, e0 + (lane & 31), 1024, gelu_fast(g1acc0[r]));
            st_act(X1h, X1l, row, e0 + 32 + (lane & 31), 1024, gelu_fast(g1acc1[r]));
        }
    }
    __syncthreads();   // B2b: X1 ready

    // ---- GEMM2: X2 = gelu(X1 @ W_l1^T), 32x256, K=512, 32x32x16 ----
    vf16 g2acc;
    {
        vf16 accA = vzero16(), accB = vzero16();
        #pragma unroll 2
        for (int ks = 0; ks < 32; ks += 2) {
            {
                const int k0 = ks * 16;
                vshort8 ah = ld_act32(X1h, lane, 1024, k0);
                vshort8 al = ld_act32(X1l, lane, 1024, k0);
                vshort8 bh = ld_pack(P2, wid * 32 + ks, 0, lane);
                vshort8 bl = ld_pack(P2, wid * 32 + ks, 1, lane);
                accA = MFMA32(ah, bh, accA);
                accA = MFMA32(al, bh, accA);
                accA = MFMA32(ah, bl, accA);
            }
            {
                const int k0 = ks * 16 + 16;
                vshort8 ah = ld_act32(X1h, lane, 1024, k0);
                vshort8 al = ld_act32(X1l, lane, 1024, k0);
                vshort8 bh = ld_pack(P2, wid * 32 + ks + 1, 0, lane);
                vshort8 bl = ld_pack(P2, wid * 32 + ks + 1, 1, lane);
                accB = MFMA32(ah, bh, accB);
                accB = MFMA32(al, bh, accB);
                accB = MFMA32(ah, bl, accB);
            }
        }
        g2acc = accA + accB;
    }
    __syncthreads();   // B3a: all waves done reading X1
    {
        const int e0 = wid * 32;
        #pragma unroll
        for (int r = 0; r < 16; ++r) {
            const int row = (r & 3) + 8 * (r >> 2) + 4 * (lane >> 5);
            st_act(X2h, X2l, row, e0 + (lane & 31), 512, gelu_fast(g2acc[r]));
        }
    }
    __syncthreads();   // B3b: X2 ready

    // ---- GEMM3: X3 = gelu(X2 @ W_l2^T), 32x128, K=256, 16x16x32 ----
    {
        const int e0 = wid * 16;
        vf4 acc0 = vzero4(), acc1 = vzero4();  // rows 0..15, 16..31
        #pragma unroll 2
        for (int ks = 0; ks < 8; ++ks) {
            const int k0 = ks * 32;
            vshort8 bh  = ld_pack(P3, wid * 8 + ks, 0, lane);
            vshort8 bl  = ld_pack(P3, wid * 8 + ks, 1, lane);
            vshort8 ah0 = ld_act16(X2h, lane, 512, 0, k0);
            vshort8 al0 = ld_act16(X2l, lane, 512, 0, k0);
            vshort8 ah1 = ld_act16(X2h, lane, 512, 16, k0);
            vshort8 al1 = ld_act16(X2l, lane, 512, 16, k0);
            acc0 = MFMA16(ah0, bh, acc0);
            acc1 = MFMA16(ah1, bh, acc1);
            acc0 = MFMA16(al0, bh, acc0);
            acc1 = MFMA16(al1, bh, acc1);
            acc0 = MFMA16(ah0, bl, acc0);
            acc1 = MFMA16(ah1, bl, acc1);
        }
        // X3 region [32K,49.6K) disjoint from X2 [0,32K): no pre-barrier needed
        #pragma unroll
        for (int r = 0; r < 4; ++r) {
            const int rr = ((lane >> 4) << 2) + r;
            sX3[rr * 132 + e0 + (lane & 15)]        = gelu_fast(acc0[r]);
            sX3[(rr + 16) * 132 + e0 + (lane & 15)] = gelu_fast(acc1[r]);
        }
    }
    __syncthreads();   // B4: X3 ready

    // ---- layer4 (fp32) + decision + flag ----
    {
        const int row = tid >> 4;              // 32 rows x 16 lanes
        const int j   = tid & 15;
        float p = 0.0f;
        #pragma unroll
        for (int t = 0; t < 8; ++t)
            p = fmaf(sX3[row * 132 + j + 16 * t], W_l3[j + 16 * t], p);
        #pragma unroll
        for (int off = 8; off > 0; off >>= 1)
            p += __shfl_down(p, off, 16);
        if (j == 0) {
            const float prob = 1.0f / (1.0f + expf(-p));
            const float v    = prob * prev_m[row0 + row];
            const float st   = (v > 0.5f) ? 1.0f : 0.0f;
            const float cm   = st + 1e-10f;
            sM[row] = cm;
            mask_out[row0 + row]  = st;
            currm_out[row0 + row] = cm;
            if (fabsf(v - 0.5f) < BAND) {
                const unsigned int slot = atomicAdd(ctr, 1u);
                list[slot] = row0 + row;
            }
        }
    }
    __syncthreads();   // B5: sM ready

    // ---- epilogue: out = fin * curr_m (input already in registers) ----
    #pragma unroll
    for (int it = 0; it < 8; ++it) {
        const int j = tid + NT * it;           // 4096 float4 = 32 rows x 128
        const int r = j >> 7;
        const int q = (j & 127) << 2;
        const float m = sM[r];
        const float4 v = fin[it];
        float4 o;
        o.x = v.x * m; o.y = v.y * m; o.z = v.z * m; o.w = v.w * m;
        *(float4*)&out[(size_t)(row0 + r) * D0 + q] = o;
    }
}

// ---------------- pass C: exact fp32 recompute of flagged rows ----------------
__global__ __launch_bounds__(256) void fix_rows(
    const float* __restrict__ input, const float* __restrict__ prev_m,
    const float* __restrict__ W_L, const float* __restrict__ W_l1,
    const float* __restrict__ W_l2, const float* __restrict__ W_l3,
    const unsigned int* __restrict__ ctr, const int* __restrict__ list,
    float* __restrict__ out, float* __restrict__ mask_out, float* __restrict__ currm_out)
{
    __shared__ float sx[8][512];
    __shared__ float s1[8][512];
    __shared__ float s2[8][256];
    __shared__ float s3[8][128];
    __shared__ float scm[8];
    const int tid = threadIdx.x;
    const int n = (int)*ctr;

    for (int base = blockIdx.x * 8; base < n; base += gridDim.x * 8) {
        int cnt = n - base;
        if (cnt > 8) cnt = 8;
        __syncthreads();                       // protect prev iteration LDS
        #pragma unroll
        for (int g = 0; g < 8; ++g) {
            if (g < cnt) {
                const int row = list[base + g];
                for (int j = tid; j < 512; j += 256)
                    sx[g][j] = input[(size_t)row * 512 + j];
            } else {
                for (int j = tid; j < 512; j += 256) sx[g][j] = 0.0f;
            }
        }
        __syncthreads();
        #pragma unroll
        for (int half = 0; half < 2; ++half) {
            const int e = tid + half * 256;
            const float4* wr = (const float4*)&W_L[e * 512];
            float a[8];
            #pragma unroll
            for (int g = 0; g < 8; ++g) a[g] = 0.0f;
            for (int kq = 0; kq < 128; ++kq) {
                const float4 w = wr[kq];
                #pragma unroll
                for (int g = 0; g < 8; ++g) {
                    const float4 xv = *(const float4*)&sx[g][kq * 4];
                    a[g] = fmaf(xv.x, w.x, a[g]); a[g] = fmaf(xv.y, w.y, a[g]);
                    a[g] = fmaf(xv.z, w.z, a[g]); a[g] = fmaf(xv.w, w.w, a[g]);
                }
            }
            #pragma unroll
            for (int g = 0; g < 8; ++g) s1[g][e] = gelu_exact(a[g]);
        }
        __syncthreads();
        {
            const int e = tid;
            const float4* wr = (const float4*)&W_l1[e * 512];
            float a[8];
            #pragma unroll
            for (int g = 0; g < 8; ++g) a[g] = 0.0f;
            for (int kq = 0; kq < 128; ++kq) {
                const float4 w = wr[kq];
                #pragma unroll
                for (int g = 0; g < 8; ++g) {
                    const float4 xv = *(const float4*)&s1[g][kq * 4];
                    a[g] = fmaf(xv.x, w.x, a[g]); a[g] = fmaf(xv.y, w.y, a[g]);
                    a[g] = fmaf(xv.z, w.z, a[g]); a[g] = fmaf(xv.w, w.w, a[g]);
                }
            }
            #pragma unroll
            for (int g = 0; g < 8; ++g) s2[g][e] = gelu_exact(a[g]);
        }
        __syncthreads();
        if (tid < 128) {
            const int e = tid;
            const float4* wr = (const float4*)&W_l2[e * 256];
            float a[8];
            #pragma unroll
            for (int g = 0; g < 8; ++g) a[g] = 0.0f;
            for (int kq = 0; kq < 64; ++kq) {
                const float4 w = wr[kq];
                #pragma unroll
                for (int g = 0; g < 8; ++g) {
                    const float4 xv = *(const float4*)&s2[g][kq * 4];
                    a[g] = fmaf(xv.x, w.x, a[g]); a[g] = fmaf(xv.y, w.y, a[g]);
                    a[g] = fmaf(xv.z, w.z, a[g]); a[g] = fmaf(xv.w, w.w, a[g]);
                }
            }
            #pragma unroll
            for (int g = 0; g < 8; ++g) s3[g][e] = gelu_exact(a[g]);
        }
        __syncthreads();
        if (tid < 128) {
            const int g = tid >> 4, j = tid & 15;
            float p = 0.0f;
            #pragma unroll
            for (int t = 0; t < 8; ++t)
                p = fmaf(s3[g][j + 16 * t], W_l3[j + 16 * t], p);
            #pragma unroll
            for (int off = 8; off > 0; off >>= 1)
                p += __shfl_down(p, off, 16);
            if (j == 0 && g < cnt) {
                const int row = list[base + g];
                const float prob = 1.0f / (1.0f + expf(-p));
                const float v    = prob * prev_m[row];
                const float st   = (v > 0.5f) ? 1.0f : 0.0f;
                const float cm   = st + 1e-10f;
                mask_out[row]  = st;
                currm_out[row] = cm;
                scm[g] = cm;
            }
        }
        __syncthreads();
        for (int idx = tid; idx < cnt * 128; idx += 256) {
            const int g = idx >> 7;
            const int q = (idx & 127) << 2;
            const int row = list[base + g];
            const float cm = scm[g];
            const float4 v = *(const float4*)&input[(size_t)row * 512 + q];
            float4 o;
            o.x = v.x * cm; o.y = v.y * cm; o.z = v.z * cm; o.w = v.w * cm;
            *(float4*)&out[(size_t)row * 512 + q] = o;
        }
    }
}

}  // namespace

extern "C" void kernel_launch(void* const* d_in, const int* in_sizes, int n_in,
                              void* d_out, int out_size, void* d_ws, size_t ws_size,
                              hipStream_t stream) {
    const float* input  = (const float*)d_in[0];
    // d_in[1] = attention_mask: unused by the reference computation
    const float* prev_m = (const float*)d_in[2];
    const float* W_L    = (const float*)d_in[3];
    const float* W_l1   = (const float*)d_in[4];
    const float* W_l2   = (const float*)d_in[5];
    const float* W_l3   = (const float*)d_in[6];

    float* out_p   = (float*)d_out;                  // [R, 512]
    float* mask_p  = out_p + (size_t)R_ROWS * D0;    // [R]
    float* currm_p = mask_p + R_ROWS;                // [R]

    // workspace (bytes): ctr @0, list @1024 (256KB), packed weights after
    char* ws = (char*)d_ws;
    unsigned int* ctr = (unsigned int*)ws;
    int* list = (int*)(ws + 1024);
    unsigned short* P1 = (unsigned short*)(ws + 263168);    // 1 MB
    unsigned short* P2 = (unsigned short*)(ws + 1311744);   // 512 KB
    unsigned short* P3 = (unsigned short*)(ws + 1836032);   // 128 KB
    // total ws use: 1967104 bytes

    hipMemsetAsync(ctr, 0, sizeof(unsigned int), stream);
    pack_weights<<<208, 256, 0, stream>>>(W_L, W_l1, W_l2, P1, P2, P3);
    mlp_mfma<<<R_ROWS / TM, NT, 0, stream>>>(input, prev_m, W_l3,
                                             P1, P2, P3,
                                             out_p, mask_p, currm_p, ctr, list);
    fix_rows<<<1024, 256, 0, stream>>>(input, prev_m, W_L, W_l1, W_l2, W_l3,
                                       ctr, list, out_p, mask_p, currm_p);
}

// Round 4
// 303.052 us; speedup vs baseline: 1.0088x; 1.0088x over previous
//
#include <hip/hip_runtime.h>
#include <math.h>

// infoFSM mask-scorer MLP — Round 6: TM=64 (weight-reuse doubling).
//
// R5 post-mortem: gelu_fast cut VALUBusy 41.6->28.4 (keep), but fin[]
// register-keep was spilled by regalloc (VGPR stayed 64, WRITE +16MB,
// epilogue serialized on scratch) -> reverted.
// R6 theory: each block streams 1.625MB of packed weights from L2;
// at TM=32 that is 3.3GB -> 96us at the 34.5TB/s L2 ceiling, ABOVE the
// 68us MFMA floor => k-loops are L2-bound (MfmaUtil stuck ~30). TM=64
// halves weight traffic (48us) -> all GEMM phases MFMA-bound.
// Cost: LDS 128KB+ -> 1 block/CU (8 waves). acc 4x vf16/wave in GEMM1.
//  - same 5-barrier overlay: A[128K] -> X1[128K] -> X2[0,64K)+X3[64K,97.8K)
//  - layer4: 64 rows x 8 lanes
//  - numerics identical to R4/R5 (bf16x3, band 1e-3, exact fp32 fix pass).

namespace {

constexpr int R_ROWS = 128 * 512;   // 65536
constexpr int D0 = 512, D1 = 512, D2 = 256, D3 = 128;
constexpr int TM = 64;              // rows per block (pass B)
constexpr int NT = 512;             // 8 waves

typedef __attribute__((ext_vector_type(8)))  short          vshort8;
typedef __attribute__((ext_vector_type(4)))  unsigned short vus4;
typedef __attribute__((ext_vector_type(8)))  unsigned short vus8;
typedef __attribute__((ext_vector_type(16))) float          vf16;
typedef __attribute__((ext_vector_type(4)))  float          vf4;

// ---------------- helpers ----------------
__device__ __forceinline__ unsigned short f32_to_bf16(float x) {
    unsigned int b = __float_as_uint(x);
    b += 0x7FFFu + ((b >> 16) & 1u);          // RNE (inputs finite)
    return (unsigned short)(b >> 16);
}
__device__ __forceinline__ float bf16_to_f32(unsigned short h) {
    return __uint_as_float(((unsigned int)h) << 16);
}
__device__ __forceinline__ float gelu_exact(float x) {
    return 0.5f * x * (1.0f + erff(x * 0.70710678118654752440f));
}
// A&S 7.1.26 erf: |abs err| <= 1.5e-7. Activation error ~1e-6 << bf16
// hi/lo storage error (~1e-5) << band (1e-3).
__device__ __forceinline__ float gelu_fast(float x) {
    const float s = fabsf(x) * 0.70710678118654752440f;
    const float t = __builtin_amdgcn_rcpf(fmaf(0.3275911f, s, 1.0f));
    float p = fmaf(1.061405429f, t, -1.453152027f);
    p = fmaf(p, t, 1.421413741f);
    p = fmaf(p, t, -0.284496736f);
    p = fmaf(p, t, 0.254829592f);
    p *= t;
    const float e = __builtin_amdgcn_exp2f(s * s * -1.44269504088896341f);
    float er = fmaf(-p, e, 1.0f);             // erf(|x|/sqrt2)
    er = copysignf(er, x);
    return 0.5f * x * (1.0f + er);
}
__device__ __forceinline__ vf16 vzero16() {
    vf16 v;
    #pragma unroll
    for (int i = 0; i < 16; ++i) v[i] = 0.0f;
    return v;
}
__device__ __forceinline__ vf4 vzero4() {
    vf4 v;
    #pragma unroll
    for (int i = 0; i < 4; ++i) v[i] = 0.0f;
    return v;
}

// LDS activation tiles: [row][k] bf16, XOR-swizzle bits 4..6.
__device__ __forceinline__ int swz_off(int row, int colElem, int pitchB) {
    return (row * pitchB + colElem * 2) ^ ((row & 7) << 4);
}
// 32x32 A-fragment read: row = row0 + lane&31, k = k0 + (lane>>5)*8
__device__ __forceinline__ vshort8 ld_act32(const char* base, int lane, int pitchB,
                                            int row0, int k0) {
    const int row = row0 + (lane & 31);
    const int k = k0 + ((lane >> 5) << 3);
    return *(const vshort8*)(base + swz_off(row, k, pitchB));
}
// 16x16 A-fragment read: row = row0 + lane&15, k = k0 + (lane>>4)*8
__device__ __forceinline__ vshort8 ld_act16(const char* base, int lane, int pitchB,
                                            int row0, int k0) {
    const int row = row0 + (lane & 15);
    const int k = k0 + ((lane >> 4) << 3);
    return *(const vshort8*)(base + swz_off(row, k, pitchB));
}
// packed weight fragment: P + blk*2048B + part*1024B + lane*16B
__device__ __forceinline__ vshort8 ld_pack(const unsigned short* __restrict__ P,
                                           int blk, int part, int lane) {
    return *(const vshort8*)((const char*)P + (((size_t)blk) << 11) +
                             (part << 10) + (lane << 4));
}
__device__ __forceinline__ void st_act(char* hi, char* lo, int row, int col, int pitchB, float x) {
    const unsigned short h = f32_to_bf16(x);
    const unsigned short l = f32_to_bf16(x - bf16_to_f32(h));
    const int off = swz_off(row, col, pitchB);
    *(unsigned short*)(hi + off) = h;
    *(unsigned short*)(lo + off) = l;
}

#define MFMA32(a, b, c) __builtin_amdgcn_mfma_f32_32x32x16_bf16((a), (b), (c), 0, 0, 0)
#define MFMA16(a, b, c) __builtin_amdgcn_mfma_f32_16x16x32_bf16((a), (b), (c), 0, 0, 0)

constexpr float BAND = 1e-3f;   // on v = prob*prev_m; ~70x est. bf16x3+gelu err

// ---------------- pass A: split + pack weights into fragment order ----------
// (unchanged from R4; fragment layouts independent of TM)
__global__ __launch_bounds__(256) void pack_weights(
    const float* __restrict__ W_L, const float* __restrict__ W_l1,
    const float* __restrict__ W_l2,
    unsigned short* __restrict__ P1, unsigned short* __restrict__ P2,
    unsigned short* __restrict__ P3)
{
    const int g = blockIdx.x * 256 + threadIdx.x;   // 53248 threads total
    const float* src;
    unsigned short* dst;
    int e, k, K, blk, lane;
    if (g < 32768) {
        lane = g & 63;
        const int ks = (g >> 6) & 31, nt = g >> 11;
        src = W_L; K = 512; dst = P1;
        e = nt * 32 + (lane & 31);
        k = ks * 16 + ((lane >> 5) << 3);
        blk = nt * 32 + ks;
    } else if (g < 49152) {
        const int h = g - 32768;
        lane = h & 63;
        const int ks = (h >> 6) & 31, nt = h >> 11;
        src = W_l1; K = 512; dst = P2;
        e = nt * 32 + (lane & 31);
        k = ks * 16 + ((lane >> 5) << 3);
        blk = nt * 32 + ks;
    } else {
        const int h = g - 49152;
        lane = h & 63;
        const int ks = (h >> 6) & 7, nt = h >> 9;
        src = W_l2; K = 256; dst = P3;
        e = nt * 16 + (lane & 15);
        k = ks * 32 + ((lane >> 4) << 3);
        blk = nt * 8 + ks;
    }
    const float4 v0 = *(const float4*)&src[(size_t)e * K + k];
    const float4 v1 = *(const float4*)&src[(size_t)e * K + k + 4];
    const float xs[8] = {v0.x, v0.y, v0.z, v0.w, v1.x, v1.y, v1.z, v1.w};
    vus8 hv, lv;
    #pragma unroll
    for (int j = 0; j < 8; ++j) {
        const unsigned short h = f32_to_bf16(xs[j]);
        hv[j] = h;
        lv[j] = f32_to_bf16(xs[j] - bf16_to_f32(h));
    }
    unsigned short* base = dst + ((size_t)blk << 10);   // 1024 shorts per blk
    *(vus8*)(base + lane * 8)       = hv;
    *(vus8*)(base + 512 + lane * 8) = lv;
}

// ---------------- pass B: fused MFMA MLP, TM=64 ----------------
// LDS overlay (bytes), one 128KB region + sM:
//   stage A:  Ahi [0,64K)   Alo [64K,128K)       pitch 1024, 64 rows
//   GEMM1 ep: X1h [0,64K)   X1l [64K,128K)       pitch 1024  (A dead)
//   GEMM2 ep: X2h [0,32K)   X2l [32K,64K)        pitch 512   (X1 dead)
//   GEMM3 ep: X3  [64K, 64K+33792) f32 pitch 132 (X1l dead; disjoint from X2)
//   sM at [131072, 131328)
constexpr int SMEM_BYTES = 131072 + 256;

__global__ __launch_bounds__(NT, 2) void mlp_mfma(
    const float* __restrict__ input, const float* __restrict__ prev_m,
    const float* __restrict__ W_l3,
    const unsigned short* __restrict__ P1, const unsigned short* __restrict__ P2,
    const unsigned short* __restrict__ P3,
    float* __restrict__ out, float* __restrict__ mask_out, float* __restrict__ currm_out,
    unsigned int* __restrict__ ctr, int* __restrict__ list)
{
    __shared__ __attribute__((aligned(16))) char smem[SMEM_BYTES];
    char* Ahi = smem;
    char* Alo = smem + 65536;
    char* X1h = smem;
    char* X1l = smem + 65536;
    char* X2h = smem;
    char* X2l = smem + 32768;
    float* sX3 = (float*)(smem + 65536);      // [64][132] f32 = 33792 B
    float* sM  = (float*)(smem + 131072);     // [64]

    const int tid  = threadIdx.x;
    const int lane = tid & 63;
    const int wid  = tid >> 6;
    const int row0 = blockIdx.x * TM;

    // ---- stage A: 64 input rows -> bf16 hi/lo, swizzled ----
    #pragma unroll
    for (int i = 0; i < 16; ++i) {
        const int c  = i * NT + tid;           // 0..8191 float4-chunks
        const int r  = c >> 7;                 // 0..63
        const int kq = (c & 127) << 2;
        const float4 v = *(const float4*)&input[(size_t)(row0 + r) * D0 + kq];
        const unsigned short h0 = f32_to_bf16(v.x);
        const unsigned short h1 = f32_to_bf16(v.y);
        const unsigned short h2 = f32_to_bf16(v.z);
        const unsigned short h3 = f32_to_bf16(v.w);
        const unsigned short l0 = f32_to_bf16(v.x - bf16_to_f32(h0));
        const unsigned short l1 = f32_to_bf16(v.y - bf16_to_f32(h1));
        const unsigned short l2 = f32_to_bf16(v.z - bf16_to_f32(h2));
        const unsigned short l3 = f32_to_bf16(v.w - bf16_to_f32(h3));
        vus4 hv = {h0, h1, h2, h3};
        vus4 lv = {l0, l1, l2, l3};
        const int off = (r * 1024 + kq * 2) ^ ((r & 7) << 4);
        *(vus4*)(Ahi + off) = hv;
        *(vus4*)(Alo + off) = lv;
    }
    __syncthreads();   // B1: A staged

    // ---- GEMM1: X1 = gelu(A @ W_L^T), 64x512, K=512, 32x32x16 ----
    vf16 g1a00, g1a01, g1a10, g1a11;   // [m-tile][n-tile]
    {
        const int nt0 = wid * 2;               // wave owns n-tiles nt0, nt0+1
        vf16 a00 = vzero16(), a01 = vzero16(), a10 = vzero16(), a11 = vzero16();
        #pragma unroll 2
        for (int ks = 0; ks < 32; ++ks) {
            const int k0 = ks * 16;
            vshort8 ah0 = ld_act32(Ahi, lane, 1024, 0,  k0);
            vshort8 al0 = ld_act32(Alo, lane, 1024, 0,  k0);
            vshort8 ah1 = ld_act32(Ahi, lane, 1024, 32, k0);
            vshort8 al1 = ld_act32(Alo, lane, 1024, 32, k0);
            vshort8 b0h = ld_pack(P1, nt0 * 32 + ks, 0, lane);
            vshort8 b0l = ld_pack(P1, nt0 * 32 + ks, 1, lane);
            vshort8 b1h = ld_pack(P1, (nt0 + 1) * 32 + ks, 0, lane);
            vshort8 b1l = ld_pack(P1, (nt0 + 1) * 32 + ks, 1, lane);
            a00 = MFMA32(ah0, b0h, a00);
            a01 = MFMA32(ah0, b1h, a01);
            a10 = MFMA32(ah1, b0h, a10);
            a11 = MFMA32(ah1, b1h, a11);
            a00 = MFMA32(al0, b0h, a00);
            a01 = MFMA32(al0, b1h, a01);
            a10 = MFMA32(al1, b0h, a10);
            a11 = MFMA32(al1, b1h, a11);
            a00 = MFMA32(ah0, b0l, a00);
            a01 = MFMA32(ah0, b1l, a01);
            a10 = MFMA32(ah1, b0l, a10);
            a11 = MFMA32(ah1, b1l, a11);
        }
        g1a00 = a00; g1a01 = a01; g1a10 = a10; g1a11 = a11;
    }
    __syncthreads();   // B2a: all waves done reading A
    {
        const int e0 = wid * 64;
        #pragma unroll
        for (int r = 0; r < 16; ++r) {
            const int rr = (r & 3) + 8 * (r >> 2) + 4 * (lane >> 5);
            st_act(X1h, X1l, rr,      e0 + (lane & 31),      1024, gelu_fast(g1a00[r]));
            st_act(X1h, X1l, rr,      e0 + 32 + (lane & 31), 1024, gelu_fast(g1a01[r]));
            st_act(X1h, X1l, rr + 32, e0 + (lane & 31),      1024, gelu_fast(g1a10[r]));
            st_act(X1h, X1l, rr + 32, e0 + 32 + (lane & 31), 1024, gelu_fast(g1a11[r]));
        }
    }
    __syncthreads();   // B2b: X1 ready

    // ---- GEMM2: X2 = gelu(X1 @ W_l1^T), 64x256, K=512, 32x32x16 ----
    vf16 g2a0, g2a1;   // m-tiles 0,1 (wave owns n-tile wid)
    {
        vf16 a0A = vzero16(), a1A = vzero16();
        vf16 a0B = vzero16(), a1B = vzero16();
        #pragma unroll 2
        for (int ks = 0; ks < 32; ks += 2) {
            {
                const int k0 = ks * 16;
                vshort8 ah0 = ld_act32(X1h, lane, 1024, 0,  k0);
                vshort8 al0 = ld_act32(X1l, lane, 1024, 0,  k0);
                vshort8 ah1 = ld_act32(X1h, lane, 1024, 32, k0);
                vshort8 al1 = ld_act32(X1l, lane, 1024, 32, k0);
                vshort8 bh = ld_pack(P2, wid * 32 + ks, 0, lane);
                vshort8 bl = ld_pack(P2, wid * 32 + ks, 1, lane);
                a0A = MFMA32(ah0, bh, a0A);
                a1A = MFMA32(ah1, bh, a1A);
                a0A = MFMA32(al0, bh, a0A);
                a1A = MFMA32(al1, bh, a1A);
                a0A = MFMA32(ah0, bl, a0A);
                a1A = MFMA32(ah1, bl, a1A);
            }
            {
                const int k0 = ks * 16 + 16;
                vshort8 ah0 = ld_act32(X1h, lane, 1024, 0,  k0);
                vshort8 al0 = ld_act32(X1l, lane, 1024, 0,  k0);
                vshort8 ah1 = ld_act32(X1h, lane, 1024, 32, k0);
                vshort8 al1 = ld_act32(X1l, lane, 1024, 32, k0);
                vshort8 bh = ld_pack(P2, wid * 32 + ks + 1, 0, lane);
                vshort8 bl = ld_pack(P2, wid * 32 + ks + 1, 1, lane);
                a0B = MFMA32(ah0, bh, a0B);
                a1B = MFMA32(ah1, bh, a1B);
                a0B = MFMA32(al0, bh, a0B);
                a1B = MFMA32(al1, bh, a1B);
                a0B = MFMA32(ah0, bl, a0B);
                a1B = MFMA32(ah1, bl, a1B);
            }
        }
        g2a0 = a0A + a0B; g2a1 = a1A + a1B;
    }
    __syncthreads();   // B3a: all waves done reading X1
    {
        const int e0 = wid * 32;
        #pragma unroll
        for (int r = 0; r < 16; ++r) {
            const int rr = (r & 3) + 8 * (r >> 2) + 4 * (lane >> 5);
            st_act(X2h, X2l, rr,      e0 + (lane & 31), 512, gelu_fast(g2a0[r]));
            st_act(X2h, X2l, rr + 32, e0 + (lane & 31), 512, gelu_fast(g2a1[r]));
        }
    }
    __syncthreads();   // B3b: X2 ready

    // ---- GEMM3: X3 = gelu(X2 @ W_l2^T), 64x128, K=256, 16x16x32 ----
    {
        const int e0 = wid * 16;               // wave owns n-tile wid
        vf4 ac[4];                             // m-tiles: rows 16*mt..16*mt+15
        #pragma unroll
        for (int mt = 0; mt < 4; ++mt) ac[mt] = vzero4();
        #pragma unroll 2
        for (int ks = 0; ks < 8; ++ks) {
            const int k0 = ks * 32;
            vshort8 bh = ld_pack(P3, wid * 8 + ks, 0, lane);
            vshort8 bl = ld_pack(P3, wid * 8 + ks, 1, lane);
            #pragma unroll
            for (int mt = 0; mt < 4; ++mt) {
                vshort8 ah = ld_act16(X2h, lane, 512, mt * 16, k0);
                vshort8 al = ld_act16(X2l, lane, 512, mt * 16, k0);
                ac[mt] = MFMA16(ah, bh, ac[mt]);
                ac[mt] = MFMA16(al, bh, ac[mt]);
                ac[mt] = MFMA16(ah, bl, ac[mt]);
            }
        }
        // X3 region [64K,97.8K) overlays X1l (dead since B3a); disjoint from X2
        #pragma unroll
        for (int mt = 0; mt < 4; ++mt)
            #pragma unroll
            for (int r = 0; r < 4; ++r) {
                const int rr = mt * 16 + ((lane >> 4) << 2) + r;
                sX3[rr * 132 + e0 + (lane & 15)] = gelu_fast(ac[mt][r]);
            }
    }
    __syncthreads();   // B4: X3 ready

    // ---- layer4 (fp32) + decision + flag: 64 rows x 8 lanes ----
    {
        const int row = tid >> 3;
        const int j   = tid & 7;
        float p = 0.0f;
        #pragma unroll
        for (int t = 0; t < 16; ++t)
            p = fmaf(sX3[row * 132 + j + 8 * t], W_l3[j + 8 * t], p);
        p += __shfl_down(p, 4, 8);
        p += __shfl_down(p, 2, 8);
        p += __shfl_down(p, 1, 8);
        if (j == 0) {
            const float prob = 1.0f / (1.0f + expf(-p));
            const float v    = prob * prev_m[row0 + row];
            const float st   = (v > 0.5f) ? 1.0f : 0.0f;
            const float cm   = st + 1e-10f;
            sM[row] = cm;
            mask_out[row0 + row]  = st;
            currm_out[row0 + row] = cm;
            if (fabsf(v - 0.5f) < BAND) {
                const unsigned int slot = atomicAdd(ctr, 1u);
                list[slot] = row0 + row;
            }
        }
    }
    __syncthreads();   // B5: sM ready

    // ---- epilogue: out = input * curr_m (input re-read; L3-resident) ----
    #pragma unroll
    for (int it = 0; it < 16; ++it) {
        const int c = it * NT + tid;           // 8192 float4 = 64 rows x 128
        const int r = c >> 7;
        const int q = (c & 127) << 2;
        const float m = sM[r];
        const float4 v = *(const float4*)&input[(size_t)(row0 + r) * D0 + q];
        float4 o;
        o.x = v.x * m; o.y = v.y * m; o.z = v.z * m; o.w = v.w * m;
        *(float4*)&out[(size_t)(row0 + r) * D0 + q] = o;
    }
}

// ---------------- pass C: exact fp32 recompute of flagged rows ----------------
__global__ __launch_bounds__(256) void fix_rows(
    const float* __restrict__ input, const float* __restrict__ prev_m,
    const float* __restrict__ W_L, const float* __restrict__ W_l1,
    const float* __restrict__ W_l2, const float* __restrict__ W_l3,
    const unsigned int* __restrict__ ctr, const int* __restrict__ list,
    float* __restrict__ out, float* __restrict__ mask_out, float* __restrict__ currm_out)
{
    __shared__ float sx[8][512];
    __shared__ float s1[8][512];
    __shared__ float s2[8][256];
    __shared__ float s3[8][128];
    __shared__ float scm[8];
    const int tid = threadIdx.x;
    const int n = (int)*ctr;

    for (int base = blockIdx.x * 8; base < n; base += gridDim.x * 8) {
        int cnt = n - base;
        if (cnt > 8) cnt = 8;
        __syncthreads();                       // protect prev iteration LDS
        #pragma unroll
        for (int g = 0; g < 8; ++g) {
            if (g < cnt) {
                const int row = list[base + g];
                for (int j = tid; j < 512; j += 256)
                    sx[g][j] = input[(size_t)row * 512 + j];
            } else {
                for (int j = tid; j < 512; j += 256) sx[g][j] = 0.0f;
            }
        }
        __syncthreads();
        #pragma unroll
        for (int half = 0; half < 2; ++half) {
            const int e = tid + half * 256;
            const float4* wr = (const float4*)&W_L[e * 512];
            float a[8];
            #pragma unroll
            for (int g = 0; g < 8; ++g) a[g] = 0.0f;
            for (int kq = 0; kq < 128; ++kq) {
                const float4 w = wr[kq];
                #pragma unroll
                for (int g = 0; g < 8; ++g) {
                    const float4 xv = *(const float4*)&sx[g][kq * 4];
                    a[g] = fmaf(xv.x, w.x, a[g]); a[g] = fmaf(xv.y, w.y, a[g]);
                    a[g] = fmaf(xv.z, w.z, a[g]); a[g] = fmaf(xv.w, w.w, a[g]);
                }
            }
            #pragma unroll
            for (int g = 0; g < 8; ++g) s1[g][e] = gelu_exact(a[g]);
        }
        __syncthreads();
        {
            const int e = tid;
            const float4* wr = (const float4*)&W_l1[e * 512];
            float a[8];
            #pragma unroll
            for (int g = 0; g < 8; ++g) a[g] = 0.0f;
            for (int kq = 0; kq < 128; ++kq) {
                const float4 w = wr[kq];
                #pragma unroll
                for (int g = 0; g < 8; ++g) {
                    const float4 xv = *(const float4*)&s1[g][kq * 4];
                    a[g] = fmaf(xv.x, w.x, a[g]); a[g] = fmaf(xv.y, w.y, a[g]);
                    a[g] = fmaf(xv.z, w.z, a[g]); a[g] = fmaf(xv.w, w.w, a[g]);
                }
            }
            #pragma unroll
            for (int g = 0; g < 8; ++g) s2[g][e] = gelu_exact(a[g]);
        }
        __syncthreads();
        if (tid < 128) {
            const int e = tid;
            const float4* wr = (const float4*)&W_l2[e * 256];
            float a[8];
            #pragma unroll
            for (int g = 0; g < 8; ++g) a[g] = 0.0f;
            for (int kq = 0; kq < 64; ++kq) {
                const float4 w = wr[kq];
                #pragma unroll
                for (int g = 0; g < 8; ++g) {
                    const float4 xv = *(const float4*)&s2[g][kq * 4];
                    a[g] = fmaf(xv.x, w.x, a[g]); a[g] = fmaf(xv.y, w.y, a[g]);
                    a[g] = fmaf(xv.z, w.z, a[g]); a[g] = fmaf(xv.w, w.w, a[g]);
                }
            }
            #pragma unroll
            for (int g = 0; g < 8; ++g) s3[g][e] = gelu_exact(a[g]);
        }
        __syncthreads();
        if (tid < 128) {
            const int g = tid >> 4, j = tid & 15;
            float p = 0.0f;
            #pragma unroll
            for (int t = 0; t < 8; ++t)
                p = fmaf(s3[g][j + 16 * t], W_l3[j + 16 * t], p);
            #pragma unroll
            for (int off = 8; off > 0; off >>= 1)
                p += __shfl_down(p, off, 16);
            if (j == 0 && g < cnt) {
                const int row = list[base + g];
                const float prob = 1.0f / (1.0f + expf(-p));
                const float v    = prob * prev_m[row];
                const float st   = (v > 0.5f) ? 1.0f : 0.0f;
                const float cm   = st + 1e-10f;
                mask_out[row]  = st;
                currm_out[row] = cm;
                scm[g] = cm;
            }
        }
        __syncthreads();
        for (int idx = tid; idx < cnt * 128; idx += 256) {
            const int g = idx >> 7;
            const int q = (idx & 127) << 2;
            const int row = list[base + g];
            const float cm = scm[g];
            const float4 v = *(const float4*)&input[(size_t)row * 512 + q];
            float4 o;
            o.x = v.x * cm; o.y = v.y * cm; o.z = v.z * cm; o.w = v.w * cm;
            *(float4*)&out[(size_t)row * 512 + q] = o;
        }
    }
}

}  // namespace

extern "C" void kernel_launch(void* const* d_in, const int* in_sizes, int n_in,
                              void* d_out, int out_size, void* d_ws, size_t ws_size,
                              hipStream_t stream) {
    const float* input  = (const float*)d_in[0];
    // d_in[1] = attention_mask: unused by the reference computation
    const float* prev_m = (const float*)d_in[2];
    const float* W_L    = (const float*)d_in[3];
    const float* W_l1   = (const float*)d_in[4];
    const float* W_l2   = (const float*)d_in[5];
    const float* W_l3   = (const float*)d_in[6];

    float* out_p   = (float*)d_out;                  // [R, 512]
    float* mask_p  = out_p + (size_t)R_ROWS * D0;    // [R]
    float* currm_p = mask_p + R_ROWS;                // [R]

    // workspace (bytes): ctr @0, list @1024 (256KB), packed weights after
    char* ws = (char*)d_ws;
    unsigned int* ctr = (unsigned int*)ws;
    int* list = (int*)(ws + 1024);
    unsigned short* P1 = (unsigned short*)(ws + 263168);    // 1 MB
    unsigned short* P2 = (unsigned short*)(ws + 1311744);   // 512 KB
    unsigned short* P3 = (unsigned short*)(ws + 1836032);   // 128 KB
    // total ws use: 1967104 bytes

    hipMemsetAsync(ctr, 0, sizeof(unsigned int), stream);
    pack_weights<<<208, 256, 0, stream>>>(W_L, W_l1, W_l2, P1, P2, P3);
    mlp_mfma<<<R_ROWS / TM, NT, 0, stream>>>(input, prev_m, W_l3,
                                             P1, P2, P3,
                                             out_p, mask_p, currm_p, ctr, list);
    fix_rows<<<1024, 256, 0, stream>>>(input, prev_m, W_L, W_l1, W_l2, W_l3,
                                       ctr, list, out_p, mask_p, currm_p);
}

// Round 5
// 302.537 us; speedup vs baseline: 1.0105x; 1.0017x over previous
//
#include <hip/hip_runtime.h>
#include <math.h>

// infoFSM mask-scorer MLP — Round 7: register-software-pipelined k-loops.
//
// Evidence R4-R6: L2-BW halving (TM=64) neutral, VALU -13pts neutral,
// occupancy halving neutral -> k-loops are LATENCY-bound: every ks exposes
// an L2/LDS wait before its MFMA burst (2 waves/SIMD can't cover it), and
// GEMM3 had 16-cyc accumulator dep gaps. R7 (VGPR budget 256 at 2 w/SIMD,
// only 100 used):
//  - double-buffer A-frags (ds) and B-frags (global) one ks ahead in [2]
//    register buffers (static idx via ks&1 + unroll 2)
//  - prologue loads hoisted above the preceding barrier
//  - GEMM2: 6 independent acc chains; GEMM3: term-major MFMA order
//  - everything else identical to R6 (TM=64, gelu_fast, bf16x3, band+fix).

namespace {

constexpr int R_ROWS = 128 * 512;   // 65536
constexpr int D0 = 512, D1 = 512, D2 = 256, D3 = 128;
constexpr int TM = 64;              // rows per block (pass B)
constexpr int NT = 512;             // 8 waves

typedef __attribute__((ext_vector_type(8)))  short          vshort8;
typedef __attribute__((ext_vector_type(4)))  unsigned short vus4;
typedef __attribute__((ext_vector_type(8)))  unsigned short vus8;
typedef __attribute__((ext_vector_type(16))) float          vf16;
typedef __attribute__((ext_vector_type(4)))  float          vf4;

// ---------------- helpers ----------------
__device__ __forceinline__ unsigned short f32_to_bf16(float x) {
    unsigned int b = __float_as_uint(x);
    b += 0x7FFFu + ((b >> 16) & 1u);          // RNE (inputs finite)
    return (unsigned short)(b >> 16);
}
__device__ __forceinline__ float bf16_to_f32(unsigned short h) {
    return __uint_as_float(((unsigned int)h) << 16);
}
__device__ __forceinline__ float gelu_exact(float x) {
    return 0.5f * x * (1.0f + erff(x * 0.70710678118654752440f));
}
// A&S 7.1.26 erf: |abs err| <= 1.5e-7. Activation error ~1e-6 << bf16
// hi/lo storage error (~1e-5) << band (1e-3).
__device__ __forceinline__ float gelu_fast(float x) {
    const float s = fabsf(x) * 0.70710678118654752440f;
    const float t = __builtin_amdgcn_rcpf(fmaf(0.3275911f, s, 1.0f));
    float p = fmaf(1.061405429f, t, -1.453152027f);
    p = fmaf(p, t, 1.421413741f);
    p = fmaf(p, t, -0.284496736f);
    p = fmaf(p, t, 0.254829592f);
    p *= t;
    const float e = __builtin_amdgcn_exp2f(s * s * -1.44269504088896341f);
    float er = fmaf(-p, e, 1.0f);             // erf(|x|/sqrt2)
    er = copysignf(er, x);
    return 0.5f * x * (1.0f + er);
}
__device__ __forceinline__ vf16 vzero16() {
    vf16 v;
    #pragma unroll
    for (int i = 0; i < 16; ++i) v[i] = 0.0f;
    return v;
}
__device__ __forceinline__ vf4 vzero4() {
    vf4 v;
    #pragma unroll
    for (int i = 0; i < 4; ++i) v[i] = 0.0f;
    return v;
}

// LDS activation tiles: [row][k] bf16, XOR-swizzle bits 4..6.
__device__ __forceinline__ int swz_off(int row, int colElem, int pitchB) {
    return (row * pitchB + colElem * 2) ^ ((row & 7) << 4);
}
// 32x32 A-fragment read: row = row0 + lane&31, k = k0 + (lane>>5)*8
__device__ __forceinline__ vshort8 ld_act32(const char* base, int lane, int pitchB,
                                            int row0, int k0) {
    const int row = row0 + (lane & 31);
    const int k = k0 + ((lane >> 5) << 3);
    return *(const vshort8*)(base + swz_off(row, k, pitchB));
}
// 16x16 A-fragment read: row = row0 + lane&15, k = k0 + (lane>>4)*8
__device__ __forceinline__ vshort8 ld_act16(const char* base, int lane, int pitchB,
                                            int row0, int k0) {
    const int row = row0 + (lane & 15);
    const int k = k0 + ((lane >> 4) << 3);
    return *(const vshort8*)(base + swz_off(row, k, pitchB));
}
// packed weight fragment: P + blk*2048B + part*1024B + lane*16B
__device__ __forceinline__ vshort8 ld_pack(const unsigned short* __restrict__ P,
                                           int blk, int part, int lane) {
    return *(const vshort8*)((const char*)P + (((size_t)blk) << 11) +
                             (part << 10) + (lane << 4));
}
__device__ __forceinline__ void st_act(char* hi, char* lo, int row, int col, int pitchB, float x) {
    const unsigned short h = f32_to_bf16(x);
    const unsigned short l = f32_to_bf16(x - bf16_to_f32(h));
    const int off = swz_off(row, col, pitchB);
    *(unsigned short*)(hi + off) = h;
    *(unsigned short*)(lo + off) = l;
}

#define MFMA32(a, b, c) __builtin_amdgcn_mfma_f32_32x32x16_bf16((a), (b), (c), 0, 0, 0)
#define MFMA16(a, b, c) __builtin_amdgcn_mfma_f32_16x16x32_bf16((a), (b), (c), 0, 0, 0)

constexpr float BAND = 1e-3f;   // on v = prob*prev_m; ~70x est. bf16x3+gelu err

// ---------------- pass A: split + pack weights into fragment order ----------
__global__ __launch_bounds__(256) void pack_weights(
    const float* __restrict__ W_L, const float* __restrict__ W_l1,
    const float* __restrict__ W_l2,
    unsigned short* __restrict__ P1, unsigned short* __restrict__ P2,
    unsigned short* __restrict__ P3)
{
    const int g = blockIdx.x * 256 + threadIdx.x;   // 53248 threads total
    const float* src;
    unsigned short* dst;
    int e, k, K, blk, lane;
    if (g < 32768) {
        lane = g & 63;
        const int ks = (g >> 6) & 31, nt = g >> 11;
        src = W_L; K = 512; dst = P1;
        e = nt * 32 + (lane & 31);
        k = ks * 16 + ((lane >> 5) << 3);
        blk = nt * 32 + ks;
    } else if (g < 49152) {
        const int h = g - 32768;
        lane = h & 63;
        const int ks = (h >> 6) & 31, nt = h >> 11;
        src = W_l1; K = 512; dst = P2;
        e = nt * 32 + (lane & 31);
        k = ks * 16 + ((lane >> 5) << 3);
        blk = nt * 32 + ks;
    } else {
        const int h = g - 49152;
        lane = h & 63;
        const int ks = (h >> 6) & 7, nt = h >> 9;
        src = W_l2; K = 256; dst = P3;
        e = nt * 16 + (lane & 15);
        k = ks * 32 + ((lane >> 4) << 3);
        blk = nt * 8 + ks;
    }
    const float4 v0 = *(const float4*)&src[(size_t)e * K + k];
    const float4 v1 = *(const float4*)&src[(size_t)e * K + k + 4];
    const float xs[8] = {v0.x, v0.y, v0.z, v0.w, v1.x, v1.y, v1.z, v1.w};
    vus8 hv, lv;
    #pragma unroll
    for (int j = 0; j < 8; ++j) {
        const unsigned short h = f32_to_bf16(xs[j]);
        hv[j] = h;
        lv[j] = f32_to_bf16(xs[j] - bf16_to_f32(h));
    }
    unsigned short* base = dst + ((size_t)blk << 10);   // 1024 shorts per blk
    *(vus8*)(base + lane * 8)       = hv;
    *(vus8*)(base + 512 + lane * 8) = lv;
}

// ---------------- pass B: fused MFMA MLP, TM=64, pipelined k-loops ----------
// LDS overlay (bytes), one 128KB region + sM:
//   stage A:  Ahi [0,64K)   Alo [64K,128K)       pitch 1024, 64 rows
//   GEMM1 ep: X1h [0,64K)   X1l [64K,128K)       pitch 1024  (A dead)
//   GEMM2 ep: X2h [0,32K)   X2l [32K,64K)        pitch 512   (X1 dead)
//   GEMM3 ep: X3  [64K, 64K+33792) f32 pitch 132 (X1l dead; disjoint from X2)
//   sM at [131072, 131328)
constexpr int SMEM_BYTES = 131072 + 256;

__global__ __launch_bounds__(NT, 2) void mlp_mfma(
    const float* __restrict__ input, const float* __restrict__ prev_m,
    const float* __restrict__ W_l3,
    const unsigned short* __restrict__ P1, const unsigned short* __restrict__ P2,
    const unsigned short* __restrict__ P3,
    float* __restrict__ out, float* __restrict__ mask_out, float* __restrict__ currm_out,
    unsigned int* __restrict__ ctr, int* __restrict__ list)
{
    __shared__ __attribute__((aligned(16))) char smem[SMEM_BYTES];
    char* Ahi = smem;
    char* Alo = smem + 65536;
    char* X1h = smem;
    char* X1l = smem + 65536;
    char* X2h = smem;
    char* X2l = smem + 32768;
    float* sX3 = (float*)(smem + 65536);      // [64][132] f32 = 33792 B
    float* sM  = (float*)(smem + 131072);     // [64]

    const int tid  = threadIdx.x;
    const int lane = tid & 63;
    const int wid  = tid >> 6;
    const int row0 = blockIdx.x * TM;
    const int nt0  = wid * 2;

    // GEMM1 ks=0 B prologue: issue before staging so L2 latency hides under
    // the HBM staging loads + barrier.
    vshort8 g1pB0H = ld_pack(P1, nt0 * 32,       0, lane);
    vshort8 g1pB0L = ld_pack(P1, nt0 * 32,       1, lane);
    vshort8 g1pB1H = ld_pack(P1, (nt0 + 1) * 32, 0, lane);
    vshort8 g1pB1L = ld_pack(P1, (nt0 + 1) * 32, 1, lane);

    // ---- stage A: 64 input rows -> bf16 hi/lo, swizzled ----
    #pragma unroll
    for (int i = 0; i < 16; ++i) {
        const int c  = i * NT + tid;           // 0..8191 float4-chunks
        const int r  = c >> 7;                 // 0..63
        const int kq = (c & 127) << 2;
        const float4 v = *(const float4*)&input[(size_t)(row0 + r) * D0 + kq];
        const unsigned short h0 = f32_to_bf16(v.x);
        const unsigned short h1 = f32_to_bf16(v.y);
        const unsigned short h2 = f32_to_bf16(v.z);
        const unsigned short h3 = f32_to_bf16(v.w);
        const unsigned short l0 = f32_to_bf16(v.x - bf16_to_f32(h0));
        const unsigned short l1 = f32_to_bf16(v.y - bf16_to_f32(h1));
        const unsigned short l2 = f32_to_bf16(v.z - bf16_to_f32(h2));
        const unsigned short l3 = f32_to_bf16(v.w - bf16_to_f32(h3));
        vus4 hv = {h0, h1, h2, h3};
        vus4 lv = {l0, l1, l2, l3};
        const int off = (r * 1024 + kq * 2) ^ ((r & 7) << 4);
        *(vus4*)(Ahi + off) = hv;
        *(vus4*)(Alo + off) = lv;
    }
    __syncthreads();   // B1: A staged

    // ---- GEMM1: X1 = gelu(A @ W_L^T), 64x512, K=512, 32x32x16, pipelined ----
    vf16 g1a00, g1a01, g1a10, g1a11;
    {
        vshort8 B0H[2], B0L[2], B1H[2], B1L[2];
        vshort8 AH0[2], AL0[2], AH1[2], AL1[2];
        B0H[0] = g1pB0H; B0L[0] = g1pB0L; B1H[0] = g1pB1H; B1L[0] = g1pB1L;
        AH0[0] = ld_act32(Ahi, lane, 1024, 0,  0);
        AL0[0] = ld_act32(Alo, lane, 1024, 0,  0);
        AH1[0] = ld_act32(Ahi, lane, 1024, 32, 0);
        AL1[0] = ld_act32(Alo, lane, 1024, 32, 0);
        vf16 a00 = vzero16(), a01 = vzero16(), a10 = vzero16(), a11 = vzero16();
        #pragma unroll 2
        for (int ks = 0; ks < 32; ++ks) {
            const int cur = ks & 1, nxt = cur ^ 1;
            if (ks < 31) {
                const int kn = (ks + 1) * 16;
                B0H[nxt] = ld_pack(P1, nt0 * 32 + ks + 1,       0, lane);
                B0L[nxt] = ld_pack(P1, nt0 * 32 + ks + 1,       1, lane);
                B1H[nxt] = ld_pack(P1, (nt0 + 1) * 32 + ks + 1, 0, lane);
                B1L[nxt] = ld_pack(P1, (nt0 + 1) * 32 + ks + 1, 1, lane);
                AH0[nxt] = ld_act32(Ahi, lane, 1024, 0,  kn);
                AL0[nxt] = ld_act32(Alo, lane, 1024, 0,  kn);
                AH1[nxt] = ld_act32(Ahi, lane, 1024, 32, kn);
                AL1[nxt] = ld_act32(Alo, lane, 1024, 32, kn);
            }
            a00 = MFMA32(AH0[cur], B0H[cur], a00);
            a01 = MFMA32(AH0[cur], B1H[cur], a01);
            a10 = MFMA32(AH1[cur], B0H[cur], a10);
            a11 = MFMA32(AH1[cur], B1H[cur], a11);
            a00 = MFMA32(AL0[cur], B0H[cur], a00);
            a01 = MFMA32(AL0[cur], B1H[cur], a01);
            a10 = MFMA32(AL1[cur], B0H[cur], a10);
            a11 = MFMA32(AL1[cur], B1H[cur], a11);
            a00 = MFMA32(AH0[cur], B0L[cur], a00);
            a01 = MFMA32(AH0[cur], B1L[cur], a01);
            a10 = MFMA32(AH1[cur], B0L[cur], a10);
            a11 = MFMA32(AH1[cur], B1L[cur], a11);
        }
        g1a00 = a00; g1a01 = a01; g1a10 = a10; g1a11 = a11;
    }
    // GEMM2 ks=0 B prologue (global; legal across the barrier)
    vshort8 g2pBH = ld_pack(P2, wid * 32, 0, lane);
    vshort8 g2pBL = ld_pack(P2, wid * 32, 1, lane);
    __syncthreads();   // B2a: all waves done reading A
    {
        const int e0 = wid * 64;
        #pragma unroll
        for (int r = 0; r < 16; ++r) {
            const int rr = (r & 3) + 8 * (r >> 2) + 4 * (lane >> 5);
            st_act(X1h, X1l, rr,      e0 + (lane & 31),      1024, gelu_fast(g1a00[r]));
            st_act(X1h, X1l, rr,      e0 + 32 + (lane & 31), 1024, gelu_fast(g1a01[r]));
            st_act(X1h, X1l, rr + 32, e0 + (lane & 31),      1024, gelu_fast(g1a10[r]));
            st_act(X1h, X1l, rr + 32, e0 + 32 + (lane & 31), 1024, gelu_fast(g1a11[r]));
        }
    }
    __syncthreads();   // B2b: X1 ready

    // ---- GEMM2: X2 = gelu(X1 @ W_l1^T), 64x256, K=512, 6 chains, pipelined --
    vf16 g2a0, g2a1;
    {
        vshort8 BH[2], BL[2], AH0[2], AL0[2], AH1[2], AL1[2];
        BH[0] = g2pBH; BL[0] = g2pBL;
        AH0[0] = ld_act32(X1h, lane, 1024, 0,  0);
        AL0[0] = ld_act32(X1l, lane, 1024, 0,  0);
        AH1[0] = ld_act32(X1h, lane, 1024, 32, 0);
        AL1[0] = ld_act32(X1l, lane, 1024, 32, 0);
        vf16 h0 = vzero16(), h1 = vzero16();
        vf16 p0 = vzero16(), p1 = vzero16();
        vf16 q0 = vzero16(), q1 = vzero16();
        #pragma unroll 2
        for (int ks = 0; ks < 32; ++ks) {
            const int cur = ks & 1, nxt = cur ^ 1;
            if (ks < 31) {
                const int kn = (ks + 1) * 16;
                BH[nxt] = ld_pack(P2, wid * 32 + ks + 1, 0, lane);
                BL[nxt] = ld_pack(P2, wid * 32 + ks + 1, 1, lane);
                AH0[nxt] = ld_act32(X1h, lane, 1024, 0,  kn);
                AL0[nxt] = ld_act32(X1l, lane, 1024, 0,  kn);
                AH1[nxt] = ld_act32(X1h, lane, 1024, 32, kn);
                AL1[nxt] = ld_act32(X1l, lane, 1024, 32, kn);
            }
            h0 = MFMA32(AH0[cur], BH[cur], h0);
            h1 = MFMA32(AH1[cur], BH[cur], h1);
            p0 = MFMA32(AL0[cur], BH[cur], p0);
            p1 = MFMA32(AL1[cur], BH[cur], p1);
            q0 = MFMA32(AH0[cur], BL[cur], q0);
            q1 = MFMA32(AH1[cur], BL[cur], q1);
        }
        g2a0 = h0 + p0 + q0;
        g2a1 = h1 + p1 + q1;
    }
    // GEMM3 ks=0 B prologue
    vshort8 g3pBH = ld_pack(P3, wid * 8, 0, lane);
    vshort8 g3pBL = ld_pack(P3, wid * 8, 1, lane);
    __syncthreads();   // B3a: all waves done reading X1
    {
        const int e0 = wid * 32;
        #pragma unroll
        for (int r = 0; r < 16; ++r) {
            const int rr = (r & 3) + 8 * (r >> 2) + 4 * (lane >> 5);
            st_act(X2h, X2l, rr,      e0 + (lane & 31), 512, gelu_fast(g2a0[r]));
            st_act(X2h, X2l, rr + 32, e0 + (lane & 31), 512, gelu_fast(g2a1[r]));
        }
    }
    __syncthreads();   // B3b: X2 ready

    // ---- GEMM3: X3 = gelu(X2 @ W_l2^T), 64x128, K=256, 16x16x32 ----
    {
        const int e0 = wid * 16;               // wave owns n-tile wid
        vshort8 BH[2], BL[2];
        BH[0] = g3pBH; BL[0] = g3pBL;
        vf4 hc[4], xc[4];
        #pragma unroll
        for (int mt = 0; mt < 4; ++mt) { hc[mt] = vzero4(); xc[mt] = vzero4(); }
        #pragma unroll 2
        for (int ks = 0; ks < 8; ++ks) {
            const int cur = ks & 1, nxt = cur ^ 1;
            if (ks < 7) {
                BH[nxt] = ld_pack(P3, wid * 8 + ks + 1, 0, lane);
                BL[nxt] = ld_pack(P3, wid * 8 + ks + 1, 1, lane);
            }
            const int k0 = ks * 32;
            vshort8 ah[4], al[4];
            #pragma unroll
            for (int mt = 0; mt < 4; ++mt) {
                ah[mt] = ld_act16(X2h, lane, 512, mt * 16, k0);
                al[mt] = ld_act16(X2l, lane, 512, mt * 16, k0);
            }
            // term-major order: every acc has >=4-issue dep gap
            #pragma unroll
            for (int mt = 0; mt < 4; ++mt) hc[mt] = MFMA16(ah[mt], BH[cur], hc[mt]);
            #pragma unroll
            for (int mt = 0; mt < 4; ++mt) xc[mt] = MFMA16(al[mt], BH[cur], xc[mt]);
            #pragma unroll
            for (int mt = 0; mt < 4; ++mt) xc[mt] = MFMA16(ah[mt], BL[cur], xc[mt]);
        }
        // X3 region [64K,97.8K) overlays X1l (dead since B3a); disjoint from X2
        #pragma unroll
        for (int mt = 0; mt < 4; ++mt)
            #pragma unroll
            for (int r = 0; r < 4; ++r) {
                const int rr = mt * 16 + ((lane >> 4) << 2) + r;
                sX3[rr * 132 + e0 + (lane & 15)] = gelu_fast(hc[mt][r] + xc[mt][r]);
            }
    }
    __syncthreads();   // B4: X3 ready

    // ---- layer4 (fp32) + decision + flag: 64 rows x 8 lanes ----
    {
        const int row = tid >> 3;
        const int j   = tid & 7;
        float p = 0.0f;
        #pragma unroll
        for (int t = 0; t < 16; ++t)
            p = fmaf(sX3[row * 132 + j + 8 * t], W_l3[j + 8 * t], p);
        p += __shfl_down(p, 4, 8);
        p += __shfl_down(p, 2, 8);
        p += __shfl_down(p, 1, 8);
        if (j == 0) {
            const float prob = 1.0f / (1.0f + expf(-p));
            const float v    = prob * prev_m[row0 + row];
            const float st   = (v > 0.5f) ? 1.0f : 0.0f;
            const float cm   = st + 1e-10f;
            sM[row] = cm;
            mask_out[row0 + row]  = st;
            currm_out[row0 + row] = cm;
            if (fabsf(v - 0.5f) < BAND) {
                const unsigned int slot = atomicAdd(ctr, 1u);
                list[slot] = row0 + row;
            }
        }
    }
    __syncthreads();   // B5: sM ready

    // ---- epilogue: out = input * curr_m (input re-read; L3-resident) ----
    #pragma unroll
    for (int it = 0; it < 16; ++it) {
        const int c = it * NT + tid;           // 8192 float4 = 64 rows x 128
        const int r = c >> 7;
        const int q = (c & 127) << 2;
        const float m = sM[r];
        const float4 v = *(const float4*)&input[(size_t)(row0 + r) * D0 + q];
        float4 o;
        o.x = v.x * m; o.y = v.y * m; o.z = v.z * m; o.w = v.w * m;
        *(float4*)&out[(size_t)(row0 + r) * D0 + q] = o;
    }
}

// ---------------- pass C: exact fp32 recompute of flagged rows ----------------
__global__ __launch_bounds__(256) void fix_rows(
    const float* __restrict__ input, const float* __restrict__ prev_m,
    const float* __restrict__ W_L, const float* __restrict__ W_l1,
    const float* __restrict__ W_l2, const float* __restrict__ W_l3,
    const unsigned int* __restrict__ ctr, const int* __restrict__ list,
    float* __restrict__ out, float* __restrict__ mask_out, float* __restrict__ currm_out)
{
    __shared__ float sx[8][512];
    __shared__ float s1[8][512];
    __shared__ float s2[8][256];
    __shared__ float s3[8][128];
    __shared__ float scm[8];
    const int tid = threadIdx.x;
    const int n = (int)*ctr;

    for (int base = blockIdx.x * 8; base < n; base += gridDim.x * 8) {
        int cnt = n - base;
        if (cnt > 8) cnt = 8;
        __syncthreads();                       // protect prev iteration LDS
        #pragma unroll
        for (int g = 0; g < 8; ++g) {
            if (g < cnt) {
                const int row = list[base + g];
                for (int j = tid; j < 512; j += 256)
                    sx[g][j] = input[(size_t)row * 512 + j];
            } else {
                for (int j = tid; j < 512; j += 256) sx[g][j] = 0.0f;
            }
        }
        __syncthreads();
        #pragma unroll
        for (int half = 0; half < 2; ++half) {
            const int e = tid + half * 256;
            const float4* wr = (const float4*)&W_L[e * 512];
            float a[8];
            #pragma unroll
            for (int g = 0; g < 8; ++g) a[g] = 0.0f;
            for (int kq = 0; kq < 128; ++kq) {
                const float4 w = wr[kq];
                #pragma unroll
                for (int g = 0; g < 8; ++g) {
                    const float4 xv = *(const float4*)&sx[g][kq * 4];
                    a[g] = fmaf(xv.x, w.x, a[g]); a[g] = fmaf(xv.y, w.y, a[g]);
                    a[g] = fmaf(xv.z, w.z, a[g]); a[g] = fmaf(xv.w, w.w, a[g]);
                }
            }
            #pragma unroll
            for (int g = 0; g < 8; ++g) s1[g][e] = gelu_exact(a[g]);
        }
        __syncthreads();
        {
            const int e = tid;
            const float4* wr = (const float4*)&W_l1[e * 512];
            float a[8];
            #pragma unroll
            for (int g = 0; g < 8; ++g) a[g] = 0.0f;
            for (int kq = 0; kq < 128; ++kq) {
                const float4 w = wr[kq];
                #pragma unroll
                for (int g = 0; g < 8; ++g) {
                    const float4 xv = *(const float4*)&s1[g][kq * 4];
                    a[g] = fmaf(xv.x, w.x, a[g]); a[g] = fmaf(xv.y, w.y, a[g]);
                    a[g] = fmaf(xv.z, w.z, a[g]); a[g] = fmaf(xv.w, w.w, a[g]);
                }
            }
            #pragma unroll
            for (int g = 0; g < 8; ++g) s2[g][e] = gelu_exact(a[g]);
        }
        __syncthreads();
        if (tid < 128) {
            const int e = tid;
            const float4* wr = (const float4*)&W_l2[e * 256];
            float a[8];
            #pragma unroll
            for (int g = 0; g < 8; ++g) a[g] = 0.0f;
            for (int kq = 0; kq < 64; ++kq) {
                const float4 w = wr[kq];
                #pragma unroll
                for (int g = 0; g < 8; ++g) {
                    const float4 xv = *(const float4*)&s2[g][kq * 4];
                    a[g] = fmaf(xv.x, w.x, a[g]); a[g] = fmaf(xv.y, w.y, a[g]);
                    a[g] = fmaf(xv.z, w.z, a[g]); a[g] = fmaf(xv.w, w.w, a[g]);
                }
            }
            #pragma unroll
            for (int g = 0; g < 8; ++g) s3[g][e] = gelu_exact(a[g]);
        }
        __syncthreads();
        if (tid < 128) {
            const int g = tid >> 4, j = tid & 15;
            float p = 0.0f;
            #pragma unroll
            for (int t = 0; t < 8; ++t)
                p = fmaf(s3[g][j + 16 * t], W_l3[j + 16 * t], p);
            #pragma unroll
            for (int off = 8; off > 0; off >>= 1)
                p += __shfl_down(p, off, 16);
            if (j == 0 && g < cnt) {
                const int row = list[base + g];
                const float prob = 1.0f / (1.0f + expf(-p));
                const float v    = prob * prev_m[row];
                const float st   = (v > 0.5f) ? 1.0f : 0.0f;
                const float cm   = st + 1e-10f;
                mask_out[row]  = st;
                currm_out[row] = cm;
                scm[g] = cm;
            }
        }
        __syncthreads();
        for (int idx = tid; idx < cnt * 128; idx += 256) {
            const int g = idx >> 7;
            const int q = (idx & 127) << 2;
            const int row = list[base + g];
            const float cm = scm[g];
            const float4 v = *(const float4*)&input[(size_t)row * 512 + q];
            float4 o;
            o.x = v.x * cm; o.y = v.y * cm; o.z = v.z * cm; o.w = v.w * cm;
            *(float4*)&out[(size_t)row * 512 + q] = o;
        }
    }
}

}  // namespace

extern "C" void kernel_launch(void* const* d_in, const int* in_sizes, int n_in,
                              void* d_out, int out_size, void* d_ws, size_t ws_size,
                              hipStream_t stream) {
    const float* input  = (const float*)d_in[0];
    // d_in[1] = attention_mask: unused by the reference computation
    const float* prev_m = (const float*)d_in[2];
    const float* W_L    = (const float*)d_in[3];
    const float* W_l1   = (const float*)d_in[4];
    const float* W_l2   = (const float*)d_in[5];
    const float* W_l3   = (const float*)d_in[6];

    float* out_p   = (float*)d_out;                  // [R, 512]
    float* mask_p  = out_p + (size_t)R_ROWS * D0;    // [R]
    float* currm_p = mask_p + R_ROWS;                // [R]

    // workspace (bytes): ctr @0, list @1024 (256KB), packed weights after
    char* ws = (char*)d_ws;
    unsigned int* ctr = (unsigned int*)ws;
    int* list = (int*)(ws + 1024);
    unsigned short* P1 = (unsigned short*)(ws + 263168);    // 1 MB
    unsigned short* P2 = (unsigned short*)(ws + 1311744);   // 512 KB
    unsigned short* P3 = (unsigned short*)(ws + 1836032);   // 128 KB
    // total ws use: 1967104 bytes

    hipMemsetAsync(ctr, 0, sizeof(unsigned int), stream);
    pack_weights<<<208, 256, 0, stream>>>(W_L, W_l1, W_l2, P1, P2, P3);
    mlp_mfma<<<R_ROWS / TM, NT, 0, stream>>>(input, prev_m, W_l3,
                                             P1, P2, P3,
                                             out_p, mask_p, currm_p, ctr, list);
    fix_rows<<<1024, 256, 0, stream>>>(input, prev_m, W_L, W_l1, W_l2, W_l3,
                                       ctr, list, out_p, mask_p, currm_p);
}